// Round 7
// baseline (150.879 us; speedup 1.0000x reference)
//
#include <hip/hip_runtime.h>
#include <stdint.h>

#define BATCH 4096
#define DDIM  768
#define EDIM  512
#define NSPLIT 16
#define LOG2E 1.44269504088896340736f

using short8  = __attribute__((ext_vector_type(8))) short;
using float4v = __attribute__((ext_vector_type(4))) float;

__device__ __forceinline__ unsigned short f2bf(float x) {
    union { float f; uint32_t u; } v; v.f = x;
    uint32_t u = v.u;
    u += 0x7FFFu + ((u >> 16) & 1u);   // round-to-nearest-even
    return (unsigned short)(u >> 16);
}
__device__ __forceinline__ float bf2f(unsigned short h) {
    union { uint32_t u; float f; } v; v.u = ((uint32_t)h) << 16;
    return v.f;
}

// pack 8 f32 -> 8 bf16 (RNE) via v_cvt_pk_bf16_f32 (no builtin on gfx950; T12 recipe)
__device__ __forceinline__ short8 cvt8(float4 v0, float4 v1) {
    union { short8 s8; uint32_t w[4]; } u;
    asm("v_cvt_pk_bf16_f32 %0, %1, %2" : "=v"(u.w[0]) : "v"(v0.x), "v"(v0.y));
    asm("v_cvt_pk_bf16_f32 %0, %1, %2" : "=v"(u.w[1]) : "v"(v0.z), "v"(v0.w));
    asm("v_cvt_pk_bf16_f32 %0, %1, %2" : "=v"(u.w[2]) : "v"(v1.x), "v"(v1.y));
    asm("v_cvt_pk_bf16_f32 %0, %1, %2" : "=v"(u.w[3]) : "v"(v1.z), "v"(v1.w));
    return u.s8;
}

// async global->LDS, 16B per lane; LDS dst must be wave-uniform base + lane*16
__device__ __forceinline__ void gl2lds16(const void* g, void* l) {
    __builtin_amdgcn_global_load_lds(
        (const __attribute__((address_space(1))) void*)g,
        (__attribute__((address_space(3))) void*)l, 16, 0, 0);
}

// ---------------- both W (K x N fp32) -> Wt (N x K bf16) in one launch ----------------
__global__ void transpose2(const float* __restrict__ Wa, const float* __restrict__ Wb,
                           unsigned short* __restrict__ Ta, unsigned short* __restrict__ Tb) {
    const float* W = blockIdx.z ? Wb : Wa;
    unsigned short* Wt = blockIdx.z ? Tb : Ta;
    __shared__ float tile[32][33];
    int n0 = blockIdx.x * 32, k0 = blockIdx.y * 32;
    int tid = threadIdx.x;
    for (int p = 0; p < 4; ++p) {
        int e = tid + p * 256; int lr = e >> 5, lc = e & 31;
        tile[lc][lr] = W[(size_t)(k0 + lr) * EDIM + n0 + lc];
    }
    __syncthreads();
    for (int p = 0; p < 4; ++p) {
        int e = tid + p * 256; int lr = e >> 5, lc = e & 31;
        Wt[(size_t)(n0 + lr) * DDIM + k0 + lc] = f2bf(tile[lr][lc]);
    }
}

// ---------------- fused NT GEMM (both modalities): Cbf16[4096x512] = A_fp32 @ W^T ----------------
// A read DIRECTLY as fp32 (no cvt pass): staged via global_load_lds (16B granules,
// granule-XOR swizzle p_src = p ^ (row&7)), converted to bf16 in-register with
// v_cvt_pk_bf16_f32 when building MFMA fragments.
// grid (32, 8, 2); block 256 = 4 waves; tile 128x64, wave = 32 rows x 64 cols.
// LDS: A 2x32 KB fp32 + B 2x8 KB bf16 = 80 KB.
__global__ __launch_bounds__(256) void gemm_nt(const float* __restrict__ Aimg,
                                               const float* __restrict__ Atxt,
                                               const unsigned short* __restrict__ Bimg,
                                               const unsigned short* __restrict__ Btxt,
                                               unsigned short* __restrict__ Cimg,
                                               unsigned short* __restrict__ Ctxt) {
    const float* A           = blockIdx.z ? Atxt : Aimg;
    const unsigned short* Bm = blockIdx.z ? Btxt : Bimg;
    unsigned short* C        = blockIdx.z ? Ctxt : Cimg;
    __shared__ __align__(16) float As[2][128 * 64];           // 2 x 32 KB fp32
    __shared__ __align__(16) unsigned short Bs[2][64 * 64];   // 2 x  8 KB bf16
    int tid = threadIdx.x;
    int wave = tid >> 6, lane = tid & 63;
    int q = lane >> 4, r = lane & 15;
    int m0 = blockIdx.x * 128, n0 = blockIdx.y * 64;
    int sw = (r >> 1) & 3;

    const float* gsA[8];
    float* lsA[8];
    for (int i = 0; i < 8; ++i) {
        int p = i * 256 + tid;
        int row = p >> 4, kqp = p & 15;
        int kq = kqp ^ (row & 7);
        gsA[i] = &A[(size_t)(m0 + row) * DDIM + kq * 4];
        lsA[i] = &As[0][p * 4];
    }
    const unsigned short* gsB[2];
    unsigned short* lsB[2];
    for (int i = 0; i < 2; ++i) {
        int u = i * 256 + tid;
        int kc2 = u >> 8, row = (u >> 2) & 63, kq = u & 3;
        int kq2 = kq ^ ((row >> 1) & 3);
        gsB[i] = &Bm[(size_t)(n0 + row) * DDIM + kc2 * 32 + kq2 * 8];
        lsB[i] = &Bs[0][u * 8];
    }

    float4v acc[2][4];
    for (int a = 0; a < 2; ++a)
        for (int t = 0; t < 4; ++t) acc[a][t] = (float4v){0.f, 0.f, 0.f, 0.f};

    for (int i = 0; i < 8; ++i) gl2lds16(gsA[i], lsA[i]);
    for (int i = 0; i < 2; ++i) gl2lds16(gsB[i], lsB[i]);
    __syncthreads();

    for (int it = 0; it < DDIM / 64; ++it) {
        int b = it & 1;
        if (it < DDIM / 64 - 1) {
            int k0 = (it + 1) * 64;
            for (int i = 0; i < 8; ++i) gl2lds16(gsA[i] + k0, lsA[i] + (b ^ 1) * (128 * 64));
            for (int i = 0; i < 2; ++i) gl2lds16(gsB[i] + k0, lsB[i] + (b ^ 1) * (64 * 64));
        }
        #pragma unroll
        for (int kc2 = 0; kc2 < 2; ++kc2) {
            int R0r = wave * 32 + r;
            int g0 = kc2 * 8 + (q ^ sw) * 2;           // 16B-granule index (even)
            int e = R0r & 7;                            // same for R0r and R0r+16
            int p0 = g0 ^ e, p1 = (g0 + 1) ^ e;
            float4 v0 = *(const float4*)&As[b][R0r * 64 + p0 * 4];
            float4 v1 = *(const float4*)&As[b][R0r * 64 + p1 * 4];
            float4 w0 = *(const float4*)&As[b][(R0r + 16) * 64 + p0 * 4];
            float4 w1 = *(const float4*)&As[b][(R0r + 16) * 64 + p1 * 4];
            short8 a0 = cvt8(v0, v1);
            short8 a1 = cvt8(w0, w1);
            #pragma unroll
            for (int t = 0; t < 4; ++t) {
                short8 bfr = *(const short8*)&Bs[b][kc2 * 2048 + (t * 16 + r) * 32 + (q ^ sw) * 8];
                acc[0][t] = __builtin_amdgcn_mfma_f32_16x16x32_bf16(a0, bfr, acc[0][t], 0, 0, 0);
                acc[1][t] = __builtin_amdgcn_mfma_f32_16x16x32_bf16(a1, bfr, acc[1][t], 0, 0, 0);
            }
        }
        __syncthreads();   // drains prefetch vmcnt + guards buffer reuse
    }
    for (int rg = 0; rg < 2; ++rg)
        for (int t = 0; t < 4; ++t)
            for (int g = 0; g < 4; ++g)
                C[(size_t)(m0 + wave * 32 + rg * 16 + q * 4 + g) * EDIM + n0 + t * 16 + r] =
                    f2bf(acc[rg][t][g]);
}

// ---------------- fused: inverse row norms (both) + tvals, one pass ----------------
__global__ void rnorm(const unsigned short* __restrict__ pi, const unsigned short* __restrict__ pt,
                      const int* __restrict__ labels,
                      float* __restrict__ rn_i, float* __restrict__ rn_t,
                      float* __restrict__ tout) {
    int wave = threadIdx.x >> 6, lane = threadIdx.x & 63;
    int row = blockIdx.x * 4 + wave;
    int lab = labels[row];
    union { unsigned short us[8]; uint4 u4; } a, b, c;
    a.u4 = *(const uint4*)&pi[(size_t)row * 512 + lane * 8];
    b.u4 = *(const uint4*)&pt[(size_t)row * 512 + lane * 8];
    c.u4 = *(const uint4*)&pt[(size_t)lab * 512 + lane * 8];
    float si = 0.f, st = 0.f, sl = 0.f, dt = 0.f;
    #pragma unroll
    for (int j = 0; j < 8; ++j) {
        float fa = bf2f(a.us[j]), fb = bf2f(b.us[j]), fc = bf2f(c.us[j]);
        si += fa * fa; st += fb * fb; sl += fc * fc; dt += fa * fc;
    }
    for (int off = 1; off < 64; off <<= 1) {
        si += __shfl_xor(si, off);
        st += __shfl_xor(st, off);
        sl += __shfl_xor(sl, off);
        dt += __shfl_xor(dt, off);
    }
    if (lane == 0) {
        float ri = rsqrtf(si);
        rn_i[row] = ri;
        rn_t[row] = rsqrtf(st);
        tout[row] = dt * ri * rsqrtf(sl);
    }
}

// ---------------- fused logits + fixed-max softmax sums + masked denom ----------------
// v8 = R6 structure + ONE isolated change: each wave owns 32 ROWS (two 16-row strips,
// af[2][16] = 128 VGPR) -> every B-frag ds_read feeds TWO MFMAs. Flash was measured
// LDS-read-throughput-bound (R6: 1:1 read:MFMA, ~20 us of pure b128 reads); this halves
// total LDS reads (grid halves to (16,32); per-CU reads 2x1024 -> 1x1024 per 2 blocks).
// R2's version of this idea failed from (a) launch_bounds(256,2) VGPR cap and
// (b) runtime-indexed af -> scratch; here: plain launch_bounds(256), fully unrolled
// compile-time indexing throughout.
// 16 phases of (32 cols x 256 k = 16 KB), double-buffered 2x16 KB, prefetch-before-MFMA,
// ONE barrier per phase. Grid (NSPLIT, 32): XCD = split&7 -> txt slice 512 KB, L2-resident.
// Fixed max M = alpha (|cos| <= 1); cosines recovered via acc * rn_i[row] * rn_t[col].
__global__ __launch_bounds__(256) void flash_pass(
    const unsigned short* __restrict__ img, const unsigned short* __restrict__ txt,
    const int* __restrict__ labels, const float* __restrict__ tvals,
    const float* __restrict__ rn_i, const float* __restrict__ rn_t,
    const float* __restrict__ ls,
    float* __restrict__ lP, float* __restrict__ dP) {
    __shared__ __align__(16) unsigned short Bs[2][8192];  // 2 x 16 KB
    int tid = threadIdx.x;
    int wave = tid >> 6, lane = tid & 63;
    int q = lane >> 4, r = lane & 15;
    int split = blockIdx.x;                 // fast dim -> XCD = split & 7
    int row0 = blockIdx.y * 128 + wave * 32;
    float alpha = expf(ls[0]);
    float c1 = alpha * LOG2E;               // p = exp2(c1*(cos - 1)) = e^{s - M}

    // staging coords: stage = 32 cols x 256 k bf16 = 16 KB = 4 issues x 256 thr x 16B
    int scol = (tid >> 2) & 31, skp = tid & 3;
    int skp2 = skp ^ ((scol >> 1) & 3);     // same XOR family as all verified kernels
    int sw = (r >> 1) & 3;

    const unsigned short* gsB[4];
    int lsB[4];
    for (int i = 0; i < 4; ++i) {
        int u = i * 256 + tid;
        int kc = u >> 7;
        gsB[i] = &txt[(size_t)(split * 256 + scol) * 512 + kc * 32 + skp2 * 8];
        lsB[i] = u * 8;                     // ushort offset; +buf*8192 at use
    }

    // issue stage 0 immediately so it flies under the af/labels loads
    for (int i = 0; i < 4; ++i) gl2lds16(gsB[i], &Bs[0][lsB[i]]);

    // A fragments (2 strips x 16 rows x K=512) register-resident: 128 VGPRs
    short8 af[2][16];
    #pragma unroll
    for (int st = 0; st < 2; ++st)
        #pragma unroll
        for (int kc = 0; kc < 16; ++kc)
            af[st][kc] = *(const short8*)&img[(size_t)(row0 + st * 16 + r) * 512 + kc * 32 + q * 8];

    int labr[2][4]; float tr[2][4], rnr[2][4];
    #pragma unroll
    for (int st = 0; st < 2; ++st)
        #pragma unroll
        for (int g = 0; g < 4; ++g) {
            int rw = row0 + st * 16 + q * 4 + g;
            labr[st][g] = labels[rw];
            tr[st][g] = tvals[rw];
            rnr[st][g] = rn_i[rw];
        }
    float l[2][4] = {{0.f, 0.f, 0.f, 0.f}, {0.f, 0.f, 0.f, 0.f}};
    float d[2][4] = {{0.f, 0.f, 0.f, 0.f}, {0.f, 0.f, 0.f, 0.f}};
    float4v acc[2][2];
    #pragma unroll
    for (int st = 0; st < 2; ++st)
        #pragma unroll
        for (int t = 0; t < 2; ++t) acc[st][t] = (float4v){0.f, 0.f, 0.f, 0.f};

    __syncthreads();   // stage 0 resident

    #pragma unroll
    for (int ct2 = 0; ct2 < 8; ++ct2) {
        #pragma unroll
        for (int h = 0; h < 2; ++h) {
            int s = ct2 * 2 + h;
            int buf = s & 1;
            if (s < 15) {     // prefetch stage s+1 into the other buffer BEFORE compute
                int sn = s + 1;
                int goff = (sn >> 1) * (32 * 512) + (sn & 1) * 256;
                #pragma unroll
                for (int i = 0; i < 4; ++i)
                    gl2lds16(gsB[i] + goff, &Bs[buf ^ 1][lsB[i]]);
            }
            #pragma unroll
            for (int kc = 0; kc < 8; ++kc) {
                short8 a0 = af[0][h * 8 + kc];
                short8 a1 = af[1][h * 8 + kc];
                #pragma unroll
                for (int t = 0; t < 2; ++t) {
                    short8 bf = *(const short8*)&Bs[buf][kc * 1024 + (t * 16 + r) * 32 + (q ^ sw) * 8];
                    acc[0][t] = __builtin_amdgcn_mfma_f32_16x16x32_bf16(a0, bf, acc[0][t], 0, 0, 0);
                    acc[1][t] = __builtin_amdgcn_mfma_f32_16x16x32_bf16(a1, bf, acc[1][t], 0, 0, 0);
                }
            }
            if (h == 1) {     // 32-col tile complete over full K: fold, reset acc
                int colbase = split * 256 + ct2 * 32;
                #pragma unroll
                for (int t = 0; t < 2; ++t) {
                    int cix = colbase + t * 16 + r;
                    int lc = labels[cix];
                    float rc = rn_t[cix];
                    #pragma unroll
                    for (int st = 0; st < 2; ++st) {
                        #pragma unroll
                        for (int g = 0; g < 4; ++g) {
                            float a = acc[st][t][g] * (rc * rnr[st][g]);   // cosine
                            float p = exp2f(fmaf(a, c1, -c1));
                            l[st][g] += p;
                            d[st][g] += ((a > tr[st][g]) && (lc != labr[st][g])) ? p : 0.f;
                        }
                        acc[st][t] = (float4v){0.f, 0.f, 0.f, 0.f};
                    }
                }
            }
            __syncthreads();   // drains prefetch vmcnt + guards buffer reuse
        }
    }
    #pragma unroll
    for (int st = 0; st < 2; ++st)
        #pragma unroll
        for (int g = 0; g < 4; ++g) {
            float lv = l[st][g], dv = d[st][g];
            for (int off = 1; off < 16; off <<= 1) {
                lv += __shfl_xor(lv, off);
                dv += __shfl_xor(dv, off);
            }
            if (r == 0) {
                int rw = row0 + st * 16 + q * 4 + g;
                lP[(size_t)rw * NSPLIT + split] = lv;
                dP[(size_t)rw * NSPLIT + split] = dv;
            }
        }
}

// ---------------- merge splits + per-row losses + global sum (atomic) ----------------
__global__ void combine(const float* __restrict__ lP, const float* __restrict__ dP,
                        const float* __restrict__ tvals, const float* __restrict__ ls,
                        float* __restrict__ out) {
    int row = blockIdx.x * 256 + threadIdx.x;
    float alpha = expf(ls[0]);
    float L = 0.f, D = 0.f;
    for (int s = 0; s < NSPLIT; ++s) {
        L += lP[(size_t)row * NSPLIT + s];
        D += dP[(size_t)row * NSPLIT + s];
    }
    float tm = alpha * (tvals[row] - 1.0f);   // t - M, with M = alpha
    float clip = logf(L) - tm;
    float py = expf(tm) / L;
    float cmp = (D > 0.f) ? py / (D / L + 1e-10f) : 0.f;
    float v = clip + cmp;
    for (int off = 1; off < 64; off <<= 1) v += __shfl_xor(v, off);
    __shared__ float w4[4];
    int wave = threadIdx.x >> 6, lane = threadIdx.x & 63;
    if (lane == 0) w4[wave] = v;
    __syncthreads();
    if (threadIdx.x == 0)
        atomicAdd(out, (w4[0] + w4[1] + w4[2] + w4[3]) * (1.0f / BATCH));
}

extern "C" void kernel_launch(void* const* d_in, const int* in_sizes, int n_in,
                              void* d_out, int out_size, void* d_ws, size_t ws_size,
                              hipStream_t stream) {
    const float* images = (const float*)d_in[0];
    const float* texts  = (const float*)d_in[1];
    const int*   labels = (const int*)d_in[2];
    const float* W_img  = (const float*)d_in[3];
    const float* W_txt  = (const float*)d_in[4];
    const float* lscale = (const float*)d_in[5];
    float* out = (float*)d_out;

    char* ws = (char*)d_ws;
    unsigned short* wt_img = (unsigned short*)(ws + 0);           //   786,432 B
    unsigned short* wt_txt = (unsigned short*)(ws + 786432);      //   786,432 B
    unsigned short* proj_i = (unsigned short*)(ws + 1572864);     // 4,194,304 B (bf16 raw img proj)
    unsigned short* proj_t = (unsigned short*)(ws + 5767168);     // 4,194,304 B (bf16 raw txt proj)
    float*          rn_img = (float*)(ws + 9961472);              //    16,384 B
    float*          rn_txt = (float*)(ws + 9977856);              //    16,384 B
    float*          tvals  = (float*)(ws + 9994240);              //    16,384 B
    float*          lP     = (float*)(ws + 10010624);             //   262,144 B
    float*          dP     = (float*)(ws + 10272768);             //   262,144 B

    hipMemsetAsync(out, 0, sizeof(float), stream);
    transpose2<<<dim3(EDIM / 32, DDIM / 32, 2), 256, 0, stream>>>(W_img, W_txt, wt_img, wt_txt);
    gemm_nt<<<dim3(BATCH / 128, EDIM / 64, 2), 256, 0, stream>>>(images, texts, wt_img, wt_txt,
                                                                 proj_i, proj_t);
    rnorm<<<BATCH / 4, 256, 0, stream>>>(proj_i, proj_t, labels, rn_img, rn_txt, tvals);
    flash_pass<<<dim3(NSPLIT, BATCH / 128), 256, 0, stream>>>(proj_i, proj_t, labels, tvals,
                                                              rn_img, rn_txt, lscale, lP, dP);
    combine<<<16, 256, 0, stream>>>(lP, dP, tvals, lscale, out);
}

// Round 8
// 131.641 us; speedup vs baseline: 1.1461x; 1.1461x over previous
//
#include <hip/hip_runtime.h>
#include <stdint.h>

#define BATCH 4096
#define DDIM  768
#define EDIM  512
#define NSPLIT 16
#define LOG2E 1.44269504088896340736f

using short8  = __attribute__((ext_vector_type(8))) short;
using float4v = __attribute__((ext_vector_type(4))) float;

__device__ __forceinline__ unsigned short f2bf(float x) {
    union { float f; uint32_t u; } v; v.f = x;
    uint32_t u = v.u;
    u += 0x7FFFu + ((u >> 16) & 1u);   // round-to-nearest-even
    return (unsigned short)(u >> 16);
}
__device__ __forceinline__ float bf2f(unsigned short h) {
    union { uint32_t u; float f; } v; v.u = ((uint32_t)h) << 16;
    return v.f;
}

// pack 8 f32 -> 8 bf16 (RNE) via v_cvt_pk_bf16_f32 (no builtin on gfx950; T12 recipe)
__device__ __forceinline__ short8 cvt8(float4 v0, float4 v1) {
    union { short8 s8; uint32_t w[4]; } u;
    asm("v_cvt_pk_bf16_f32 %0, %1, %2" : "=v"(u.w[0]) : "v"(v0.x), "v"(v0.y));
    asm("v_cvt_pk_bf16_f32 %0, %1, %2" : "=v"(u.w[1]) : "v"(v0.z), "v"(v0.w));
    asm("v_cvt_pk_bf16_f32 %0, %1, %2" : "=v"(u.w[2]) : "v"(v1.x), "v"(v1.y));
    asm("v_cvt_pk_bf16_f32 %0, %1, %2" : "=v"(u.w[3]) : "v"(v1.z), "v"(v1.w));
    return u.s8;
}

// async global->LDS, 16B per lane; LDS dst must be wave-uniform base + lane*16
__device__ __forceinline__ void gl2lds16(const void* g, void* l) {
    __builtin_amdgcn_global_load_lds(
        (const __attribute__((address_space(1))) void*)g,
        (__attribute__((address_space(3))) void*)l, 16, 0, 0);
}

// ---------------- both W (K x N fp32) -> Wt (N x K bf16) in one launch ----------------
__global__ void transpose2(const float* __restrict__ Wa, const float* __restrict__ Wb,
                           unsigned short* __restrict__ Ta, unsigned short* __restrict__ Tb) {
    const float* W = blockIdx.z ? Wb : Wa;
    unsigned short* Wt = blockIdx.z ? Tb : Ta;
    __shared__ float tile[32][33];
    int n0 = blockIdx.x * 32, k0 = blockIdx.y * 32;
    int tid = threadIdx.x;
    for (int p = 0; p < 4; ++p) {
        int e = tid + p * 256; int lr = e >> 5, lc = e & 31;
        tile[lc][lr] = W[(size_t)(k0 + lr) * EDIM + n0 + lc];
    }
    __syncthreads();
    for (int p = 0; p < 4; ++p) {
        int e = tid + p * 256; int lr = e >> 5, lc = e & 31;
        Wt[(size_t)(n0 + lr) * DDIM + k0 + lc] = f2bf(tile[lr][lc]);
    }
}

// ---------------- fused NT GEMM (both modalities): Cbf16[4096x512] = A_fp32 @ W^T ----------------
// A read DIRECTLY as fp32 (no cvt pass): staged via global_load_lds (16B granules,
// granule-XOR swizzle p_src = p ^ (row&7)), converted to bf16 in-register with
// v_cvt_pk_bf16_f32 when building MFMA fragments.
// grid (32, 8, 2); block 256 = 4 waves; tile 128x64, wave = 32 rows x 64 cols.
// LDS: A 2x32 KB fp32 + B 2x8 KB bf16 = 80 KB.
__global__ __launch_bounds__(256) void gemm_nt(const float* __restrict__ Aimg,
                                               const float* __restrict__ Atxt,
                                               const unsigned short* __restrict__ Bimg,
                                               const unsigned short* __restrict__ Btxt,
                                               unsigned short* __restrict__ Cimg,
                                               unsigned short* __restrict__ Ctxt) {
    const float* A           = blockIdx.z ? Atxt : Aimg;
    const unsigned short* Bm = blockIdx.z ? Btxt : Bimg;
    unsigned short* C        = blockIdx.z ? Ctxt : Cimg;
    __shared__ __align__(16) float As[2][128 * 64];           // 2 x 32 KB fp32
    __shared__ __align__(16) unsigned short Bs[2][64 * 64];   // 2 x  8 KB bf16
    int tid = threadIdx.x;
    int wave = tid >> 6, lane = tid & 63;
    int q = lane >> 4, r = lane & 15;
    int m0 = blockIdx.x * 128, n0 = blockIdx.y * 64;
    int sw = (r >> 1) & 3;

    const float* gsA[8];
    float* lsA[8];
    for (int i = 0; i < 8; ++i) {
        int p = i * 256 + tid;
        int row = p >> 4, kqp = p & 15;
        int kq = kqp ^ (row & 7);
        gsA[i] = &A[(size_t)(m0 + row) * DDIM + kq * 4];
        lsA[i] = &As[0][p * 4];
    }
    const unsigned short* gsB[2];
    unsigned short* lsB[2];
    for (int i = 0; i < 2; ++i) {
        int u = i * 256 + tid;
        int kc2 = u >> 8, row = (u >> 2) & 63, kq = u & 3;
        int kq2 = kq ^ ((row >> 1) & 3);
        gsB[i] = &Bm[(size_t)(n0 + row) * DDIM + kc2 * 32 + kq2 * 8];
        lsB[i] = &Bs[0][u * 8];
    }

    float4v acc[2][4];
    for (int a = 0; a < 2; ++a)
        for (int t = 0; t < 4; ++t) acc[a][t] = (float4v){0.f, 0.f, 0.f, 0.f};

    for (int i = 0; i < 8; ++i) gl2lds16(gsA[i], lsA[i]);
    for (int i = 0; i < 2; ++i) gl2lds16(gsB[i], lsB[i]);
    __syncthreads();

    for (int it = 0; it < DDIM / 64; ++it) {
        int b = it & 1;
        if (it < DDIM / 64 - 1) {
            int k0 = (it + 1) * 64;
            for (int i = 0; i < 8; ++i) gl2lds16(gsA[i] + k0, lsA[i] + (b ^ 1) * (128 * 64));
            for (int i = 0; i < 2; ++i) gl2lds16(gsB[i] + k0, lsB[i] + (b ^ 1) * (64 * 64));
        }
        #pragma unroll
        for (int kc2 = 0; kc2 < 2; ++kc2) {
            int R0r = wave * 32 + r;
            int g0 = kc2 * 8 + (q ^ sw) * 2;           // 16B-granule index (even)
            int e = R0r & 7;                            // same for R0r and R0r+16
            int p0 = g0 ^ e, p1 = (g0 + 1) ^ e;
            float4 v0 = *(const float4*)&As[b][R0r * 64 + p0 * 4];
            float4 v1 = *(const float4*)&As[b][R0r * 64 + p1 * 4];
            float4 w0 = *(const float4*)&As[b][(R0r + 16) * 64 + p0 * 4];
            float4 w1 = *(const float4*)&As[b][(R0r + 16) * 64 + p1 * 4];
            short8 a0 = cvt8(v0, v1);
            short8 a1 = cvt8(w0, w1);
            #pragma unroll
            for (int t = 0; t < 4; ++t) {
                short8 bfr = *(const short8*)&Bs[b][kc2 * 2048 + (t * 16 + r) * 32 + (q ^ sw) * 8];
                acc[0][t] = __builtin_amdgcn_mfma_f32_16x16x32_bf16(a0, bfr, acc[0][t], 0, 0, 0);
                acc[1][t] = __builtin_amdgcn_mfma_f32_16x16x32_bf16(a1, bfr, acc[1][t], 0, 0, 0);
            }
        }
        __syncthreads();   // drains prefetch vmcnt + guards buffer reuse
    }
    for (int rg = 0; rg < 2; ++rg)
        for (int t = 0; t < 4; ++t)
            for (int g = 0; g < 4; ++g)
                C[(size_t)(m0 + wave * 32 + rg * 16 + q * 4 + g) * EDIM + n0 + t * 16 + r] =
                    f2bf(acc[rg][t][g]);
}

// ---------------- fused: inverse row norms (both) + tvals, one pass ----------------
__global__ void rnorm(const unsigned short* __restrict__ pi, const unsigned short* __restrict__ pt,
                      const int* __restrict__ labels,
                      float* __restrict__ rn_i, float* __restrict__ rn_t,
                      float* __restrict__ tout) {
    int wave = threadIdx.x >> 6, lane = threadIdx.x & 63;
    int row = blockIdx.x * 4 + wave;
    int lab = labels[row];
    union { unsigned short us[8]; uint4 u4; } a, b, c;
    a.u4 = *(const uint4*)&pi[(size_t)row * 512 + lane * 8];
    b.u4 = *(const uint4*)&pt[(size_t)row * 512 + lane * 8];
    c.u4 = *(const uint4*)&pt[(size_t)lab * 512 + lane * 8];
    float si = 0.f, st = 0.f, sl = 0.f, dt = 0.f;
    #pragma unroll
    for (int j = 0; j < 8; ++j) {
        float fa = bf2f(a.us[j]), fb = bf2f(b.us[j]), fc = bf2f(c.us[j]);
        si += fa * fa; st += fb * fb; sl += fc * fc; dt += fa * fc;
    }
    for (int off = 1; off < 64; off <<= 1) {
        si += __shfl_xor(si, off);
        st += __shfl_xor(st, off);
        sl += __shfl_xor(sl, off);
        dt += __shfl_xor(dt, off);
    }
    if (lane == 0) {
        float ri = rsqrtf(si);
        rn_i[row] = ri;
        rn_t[row] = rsqrtf(st);
        tout[row] = dt * ri * rsqrtf(sl);
    }
}

// ---------------- fused logits + fixed-max softmax sums + masked denom ----------------
// R6 configuration EXACTLY (measured best: 133.7 us total; VGPR 124 -> 4 blocks/CU).
// R7's 32-rows/wave variant (VGPR 224, 2 blocks/CU) regressed 17 us: the binding
// resource is the staged-phase serial path hidden by block-level TLP, not LDS reads
// (profiled dur identical with half the ds_reads). Do not raise VGPR here.
// 16 phases of (32 cols x 256 k = 16 KB), double-buffered 2x16 KB, prefetch-before-MFMA,
// ONE barrier per phase. Grid (NSPLIT, 64): XCD = split&7 -> txt slice 512 KB, L2-resident.
// Fixed max M = alpha (|cos| <= 1); cosines recovered via acc * rn_i[row] * rn_t[col].
__global__ __launch_bounds__(256) void flash_pass(
    const unsigned short* __restrict__ img, const unsigned short* __restrict__ txt,
    const int* __restrict__ labels, const float* __restrict__ tvals,
    const float* __restrict__ rn_i, const float* __restrict__ rn_t,
    const float* __restrict__ ls,
    float* __restrict__ lP, float* __restrict__ dP) {
    __shared__ __align__(16) unsigned short Bs[2][8192];  // 2 x 16 KB
    int tid = threadIdx.x;
    int wave = tid >> 6, lane = tid & 63;
    int q = lane >> 4, r = lane & 15;
    int split = blockIdx.x;                 // fast dim -> XCD = split & 7
    int row0 = blockIdx.y * 64 + wave * 16;
    float alpha = expf(ls[0]);
    float c1 = alpha * LOG2E;               // p = exp2(c1*(cos - 1)) = e^{s - M}

    // staging coords: stage = 32 cols x 256 k bf16 = 16 KB = 4 issues x 256 thr x 16B
    int scol = (tid >> 2) & 31, skp = tid & 3;
    int skp2 = skp ^ ((scol >> 1) & 3);     // same XOR family as all verified kernels
    int sw = (r >> 1) & 3;

    const unsigned short* gsB[4];
    int lsB[4];
    for (int i = 0; i < 4; ++i) {
        int u = i * 256 + tid;
        int kc = u >> 7;
        gsB[i] = &txt[(size_t)(split * 256 + scol) * 512 + kc * 32 + skp2 * 8];
        lsB[i] = u * 8;                     // ushort offset; +buf*8192 at use
    }

    // issue stage 0 immediately so it flies under the af/labels loads
    for (int i = 0; i < 4; ++i) gl2lds16(gsB[i], &Bs[0][lsB[i]]);

    // A fragments (16 rows x K=512) register-resident: 64 VGPRs
    short8 af[16];
    for (int kc = 0; kc < 16; ++kc)
        af[kc] = *(const short8*)&img[(size_t)(row0 + r) * 512 + kc * 32 + q * 8];

    int labr[4]; float tr[4], rnr[4];
    for (int g = 0; g < 4; ++g) {
        int rw = row0 + q * 4 + g;
        labr[g] = labels[rw];
        tr[g] = tvals[rw];
        rnr[g] = rn_i[rw];
    }
    float l[4] = {0.f, 0.f, 0.f, 0.f}, d[4] = {0.f, 0.f, 0.f, 0.f};
    float4v acc[2];
    acc[0] = (float4v){0.f, 0.f, 0.f, 0.f};
    acc[1] = (float4v){0.f, 0.f, 0.f, 0.f};

    __syncthreads();   // stage 0 resident

    #pragma unroll
    for (int ct2 = 0; ct2 < 8; ++ct2) {
        #pragma unroll
        for (int h = 0; h < 2; ++h) {
            int s = ct2 * 2 + h;
            int buf = s & 1;
            if (s < 15) {     // prefetch stage s+1 into the other buffer BEFORE compute
                int sn = s + 1;
                int goff = (sn >> 1) * (32 * 512) + (sn & 1) * 256;
                #pragma unroll
                for (int i = 0; i < 4; ++i)
                    gl2lds16(gsB[i] + goff, &Bs[buf ^ 1][lsB[i]]);
            }
            #pragma unroll
            for (int kc = 0; kc < 8; ++kc) {
                short8 a = af[h * 8 + kc];
                #pragma unroll
                for (int t = 0; t < 2; ++t) {
                    short8 bf = *(const short8*)&Bs[buf][kc * 1024 + (t * 16 + r) * 32 + (q ^ sw) * 8];
                    acc[t] = __builtin_amdgcn_mfma_f32_16x16x32_bf16(a, bf, acc[t], 0, 0, 0);
                }
            }
            if (h == 1) {     // 32-col tile complete over full K: fold, reset acc
                int colbase = split * 256 + ct2 * 32;
                #pragma unroll
                for (int t = 0; t < 2; ++t) {
                    int cix = colbase + t * 16 + r;
                    int lc = labels[cix];
                    float rc = rn_t[cix];
                    #pragma unroll
                    for (int g = 0; g < 4; ++g) {
                        float a = acc[t][g] * (rc * rnr[g]);   // cosine
                        float p = exp2f(fmaf(a, c1, -c1));
                        l[g] += p;
                        d[g] += ((a > tr[g]) && (lc != labr[g])) ? p : 0.f;
                    }
                    acc[t] = (float4v){0.f, 0.f, 0.f, 0.f};
                }
            }
            __syncthreads();   // drains prefetch vmcnt + guards buffer reuse
        }
    }
    for (int g = 0; g < 4; ++g) {
        float lv = l[g], dv = d[g];
        for (int off = 1; off < 16; off <<= 1) {
            lv += __shfl_xor(lv, off);
            dv += __shfl_xor(dv, off);
        }
        if (r == 0) {
            int rw = row0 + q * 4 + g;
            lP[(size_t)rw * NSPLIT + split] = lv;
            dP[(size_t)rw * NSPLIT + split] = dv;
        }
    }
}

// ---------------- merge splits + per-row losses + global sum (atomic) ----------------
__global__ void combine(const float* __restrict__ lP, const float* __restrict__ dP,
                        const float* __restrict__ tvals, const float* __restrict__ ls,
                        float* __restrict__ out) {
    int row = blockIdx.x * 256 + threadIdx.x;
    float alpha = expf(ls[0]);
    float L = 0.f, D = 0.f;
    #pragma unroll
    for (int s4 = 0; s4 < NSPLIT / 4; ++s4) {   // contiguous per row: float4 loads
        float4 lv = *(const float4*)&lP[(size_t)row * NSPLIT + s4 * 4];
        float4 dv = *(const float4*)&dP[(size_t)row * NSPLIT + s4 * 4];
        L += lv.x + lv.y + lv.z + lv.w;
        D += dv.x + dv.y + dv.z + dv.w;
    }
    float tm = alpha * (tvals[row] - 1.0f);   // t - M, with M = alpha
    float clip = logf(L) - tm;
    float py = expf(tm) / L;
    float cmp = (D > 0.f) ? py / (D / L + 1e-10f) : 0.f;
    float v = clip + cmp;
    for (int off = 1; off < 64; off <<= 1) v += __shfl_xor(v, off);
    __shared__ float w4[4];
    int wave = threadIdx.x >> 6, lane = threadIdx.x & 63;
    if (lane == 0) w4[wave] = v;
    __syncthreads();
    if (threadIdx.x == 0)
        atomicAdd(out, (w4[0] + w4[1] + w4[2] + w4[3]) * (1.0f / BATCH));
}

extern "C" void kernel_launch(void* const* d_in, const int* in_sizes, int n_in,
                              void* d_out, int out_size, void* d_ws, size_t ws_size,
                              hipStream_t stream) {
    const float* images = (const float*)d_in[0];
    const float* texts  = (const float*)d_in[1];
    const int*   labels = (const int*)d_in[2];
    const float* W_img  = (const float*)d_in[3];
    const float* W_txt  = (const float*)d_in[4];
    const float* lscale = (const float*)d_in[5];
    float* out = (float*)d_out;

    char* ws = (char*)d_ws;
    unsigned short* wt_img = (unsigned short*)(ws + 0);           //   786,432 B
    unsigned short* wt_txt = (unsigned short*)(ws + 786432);      //   786,432 B
    unsigned short* proj_i = (unsigned short*)(ws + 1572864);     // 4,194,304 B (bf16 raw img proj)
    unsigned short* proj_t = (unsigned short*)(ws + 5767168);     // 4,194,304 B (bf16 raw txt proj)
    float*          rn_img = (float*)(ws + 9961472);              //    16,384 B
    float*          rn_txt = (float*)(ws + 9977856);              //    16,384 B
    float*          tvals  = (float*)(ws + 9994240);              //    16,384 B
    float*          lP     = (float*)(ws + 10010624);             //   262,144 B
    float*          dP     = (float*)(ws + 10272768);             //   262,144 B

    hipMemsetAsync(out, 0, sizeof(float), stream);
    transpose2<<<dim3(EDIM / 32, DDIM / 32, 2), 256, 0, stream>>>(W_img, W_txt, wt_img, wt_txt);
    gemm_nt<<<dim3(BATCH / 128, EDIM / 64, 2), 256, 0, stream>>>(images, texts, wt_img, wt_txt,
                                                                 proj_i, proj_t);
    rnorm<<<BATCH / 4, 256, 0, stream>>>(proj_i, proj_t, labels, rn_img, rn_txt, tvals);
    flash_pass<<<dim3(NSPLIT, BATCH / 64), 256, 0, stream>>>(proj_i, proj_t, labels, tvals,
                                                             rn_img, rn_txt, lscale, lP, dP);
    combine<<<16, 256, 0, stream>>>(lP, dP, tvals, lscale, out);
}